// Round 1
// 557.398 us; speedup vs baseline: 1.1984x; 1.1984x over previous
//
#include <hip/hip_runtime.h>
#include <hip/hip_bf16.h>

// ---- problem constants ----
#define BATCH 4
#define SEQ   2048
#define DIN   4096
#define DOUT  4096
#define MTOT  (BATCH * SEQ)     // 8192
#define RANK  16

typedef __bf16 bf8_t  __attribute__((ext_vector_type(8)));
typedef float  f4_t   __attribute__((ext_vector_type(4)));

#define GLD_LDS(g, l) \
  __builtin_amdgcn_global_load_lds((const __attribute__((address_space(1))) void*)(g), \
                                   (__attribute__((address_space(3))) void*)(l), 16, 0, 0)

// ---------------------------------------------------------------------------
// Kernel A: bulk f32 -> bf16 convert (used for weight AND x; fully coalesced)
// ---------------------------------------------------------------------------
__global__ __launch_bounds__(256) void conv_kernel(
    const float* __restrict__ w, __bf16* __restrict__ wb) {
  const size_t i = ((size_t)blockIdx.x * 256 + threadIdx.x) * 8;
  f4_t a = *(const f4_t*)(w + i);
  f4_t b = *(const f4_t*)(w + i + 4);
  bf8_t o;
#pragma unroll
  for (int e = 0; e < 4; ++e) { o[e] = (__bf16)a[e]; o[4 + e] = (__bf16)b[e]; }
  *(bf8_t*)(wb + i) = o;
}

// ---------------------------------------------------------------------------
// Kernel B: lowS[m][r] += scale * sum_k xb[m][k]*A[b][r][k]   (MFMA, k-split=8)
// Reads the already-converted bf16 xb (half the bytes of the old f32 path).
// lowS must be zeroed before launch.
// ---------------------------------------------------------------------------
__global__ __launch_bounds__(256) void lora_low_kernel(
    const __bf16* __restrict__ xb, const float* __restrict__ Aw,
    const float* __restrict__ scales, const int* __restrict__ adapter_id,
    float* __restrict__ lowS) {
  const int t    = threadIdx.x;
  const int w    = t >> 6;
  const int lane = t & 63;
  const int quad = lane >> 4;
  const int l16  = lane & 15;
  const int m0   = blockIdx.x * 64;
  const int kb   = blockIdx.y * 512;
  const int b    = adapter_id[m0 >> 11];
  const float scale = scales[b];

  const int row = m0 + w * 16 + l16;
  const __bf16* xp = xb + (size_t)row * DIN + kb + quad * 8;
  const float*  ap = Aw + ((size_t)b * RANK + l16) * DIN + kb + quad * 8;

  f4_t acc = (f4_t)0.f;
#pragma unroll 4
  for (int it = 0; it < 16; ++it) {
    const int off = it * 32;
    bf8_t af = *(const bf8_t*)(xp + off);
    f4_t v0 = *(const f4_t*)(ap + off);
    f4_t v1 = *(const f4_t*)(ap + off + 4);
    bf8_t bfr;
#pragma unroll
    for (int e = 0; e < 4; ++e) { bfr[e] = (__bf16)v0[e]; bfr[4 + e] = (__bf16)v1[e]; }
    acc = __builtin_amdgcn_mfma_f32_16x16x32_bf16(af, bfr, acc, 0, 0, 0);
  }
#pragma unroll
  for (int e = 0; e < 4; ++e)
    atomicAdd(&lowS[(size_t)(m0 + w * 16 + quad * 4 + e) * RANK + l16], acc[e] * scale);
}

// ---------------------------------------------------------------------------
// Kernel C: out = x @ W^T + bias + lowS @ loraB[b]^T   (bf16 GEMM, f32 out)
// 256x256 tile, BK=32, 8 waves (wave = 128x64 out), 4-slot LDS rotation with
// counted vmcnt (3 K-tiles in flight, never drained in main loop), raw
// s_barrier, source-side XOR swizzle -> 2-way (free) ds_read_b128 frag reads,
// s_setprio around MFMA cluster. LoRA = one zero-padded MFMA per fragment.
// ---------------------------------------------------------------------------
#define BM 256
#define BN 256
#define BKK 32
#define NT (DIN / BKK)   // 128 K-tiles

__global__ __launch_bounds__(512, 2) void lora_gemm_kernel(
    const __bf16* __restrict__ x, const __bf16* __restrict__ wgt,
    const float* __restrict__ bias, const float* __restrict__ loraB,
    const int* __restrict__ adapter_id, const float* __restrict__ lowS,
    float* __restrict__ out) {
  __shared__ __bf16 lds[4][2][BM * BKK];   // 4 slots x (A,B) x 16 KiB = 128 KiB

  const int t    = threadIdx.x;
  const int w    = t >> 6;
  const int lane = t & 63;
  const int quad = lane >> 4;
  const int l16  = lane & 15;
  const int wm   = w >> 2;        // 0..1 : 128-row band
  const int wn   = w & 3;         // 0..3 : 64-col band
  const int m0 = blockIdx.y * BM;
  const int n0 = blockIdx.x * BN;

  // ---- staging addresses -------------------------------------------------
  // LDS is written linearly by global_load_lds (wave-uniform base + lane*16B):
  // thread t covers linear 16B chunk t (rows 0..127) and t+512 (rows 128..255).
  // Source is pre-swizzled: LDS slot (t&3) of row sr holds global chunk
  // (t&3) ^ ((sr>>1)&3)  -> read side XORs the same term back (involution).
  const int sr = t >> 2;                       // 0..127
  const int sc = (t & 3) ^ ((sr >> 1) & 3);    // inverse-swizzled source chunk
  const __bf16* gA = x   + (size_t)(m0 + sr) * DIN + sc * 8;
  const __bf16* gB = wgt + (size_t)(n0 + sr) * DIN + sc * 8;
  const int ldst = w * 512;       // wave-uniform LDS base (elems); HW adds lane*16B

  // fragment-read chunk: logical chunk `quad`, stored at quad ^ ((row>>1)&3).
  // bank group = 4*(l16&1) + (quad ^ ((l16>>1)&3)) -> 8 distinct per 8 lanes,
  // exactly 2-way across 16 lanes = free.
  const int fc   = (quad ^ ((l16 >> 1) & 3)) * 8;
  const int aoff = (wm * 128 + l16) * BKK + fc;
  const int boff = (wn * 64  + l16) * BKK + fc;

  f4_t acc[8][4];
#pragma unroll
  for (int i = 0; i < 8; ++i)
#pragma unroll
    for (int j = 0; j < 4; ++j) acc[i][j] = (f4_t)0.f;

#define STAGE(s, k0) do {                                      \
    GLD_LDS(gA + (k0),              &lds[s][0][ldst]);         \
    GLD_LDS(gA + (k0) + 128 * DIN,  &lds[s][0][4096 + ldst]);  \
    GLD_LDS(gB + (k0),              &lds[s][1][ldst]);         \
    GLD_LDS(gB + (k0) + 128 * DIN,  &lds[s][1][4096 + ldst]);  \
  } while (0)

  auto body = [&](int s) {
    bf8_t a[8], b[4];
#pragma unroll
    for (int mf = 0; mf < 8; ++mf)
      a[mf] = *(const bf8_t*)&lds[s][0][aoff + mf * (16 * BKK)];
#pragma unroll
    for (int nf = 0; nf < 4; ++nf)
      b[nf] = *(const bf8_t*)&lds[s][1][boff + nf * (16 * BKK)];
    __builtin_amdgcn_s_setprio(1);
#pragma unroll
    for (int mf = 0; mf < 8; ++mf)
#pragma unroll
      for (int nf = 0; nf < 4; ++nf)
        acc[mf][nf] = __builtin_amdgcn_mfma_f32_16x16x32_bf16(a[mf], b[nf], acc[mf][nf], 0, 0, 0);
    __builtin_amdgcn_s_setprio(0);
  };

  // ---- pipelined K-loop --------------------------------------------------
  // slot(kt) = kt&3. Stage kt issued at iter kt-3 (its slot's last reads were
  // at iter kt-4, one barrier earlier). vmcnt(12) = 3 stages x 4 loads in
  // flight -> confirms this iter's slot landed. Tail peels 8/4/0.
  STAGE(0, 0); STAGE(1, BKK); STAGE(2, 2 * BKK);
  for (int it = 0; it < NT - 3; ++it) {
    STAGE((it + 3) & 3, (it + 3) * BKK);
    asm volatile("s_waitcnt vmcnt(12)" ::: "memory");
    __builtin_amdgcn_s_barrier();
    body(it & 3);
    __builtin_amdgcn_s_barrier();
  }
  asm volatile("s_waitcnt vmcnt(8)" ::: "memory");
  __builtin_amdgcn_s_barrier();
  body((NT - 3) & 3);
  __builtin_amdgcn_s_barrier();
  asm volatile("s_waitcnt vmcnt(4)" ::: "memory");
  __builtin_amdgcn_s_barrier();
  body((NT - 2) & 3);
  __builtin_amdgcn_s_barrier();
  asm volatile("s_waitcnt vmcnt(0)" ::: "memory");
  __builtin_amdgcn_s_barrier();
  body((NT - 1) & 3);
#undef STAGE

  // ---- LoRA epilogue: one zero-padded MFMA k-step (k=0..15 valid) --------
  const int b = adapter_id[m0 >> 11];
  bf8_t alow[8], blow[4];
  if (quad < 2) {
#pragma unroll
    for (int mf = 0; mf < 8; ++mf) {
      const float* p = &lowS[(size_t)(m0 + wm * 128 + mf * 16 + l16) * RANK + quad * 8];
      f4_t u0 = *(const f4_t*)p;
      f4_t u1 = *(const f4_t*)(p + 4);
#pragma unroll
      for (int e = 0; e < 4; ++e) { alow[mf][e] = (__bf16)u0[e]; alow[mf][4 + e] = (__bf16)u1[e]; }
    }
#pragma unroll
    for (int nf = 0; nf < 4; ++nf) {
      const float* p = &loraB[((size_t)b * DOUT + n0 + wn * 64 + nf * 16 + l16) * RANK + quad * 8];
      f4_t u0 = *(const f4_t*)p;
      f4_t u1 = *(const f4_t*)(p + 4);
#pragma unroll
      for (int e = 0; e < 4; ++e) { blow[nf][e] = (__bf16)u0[e]; blow[nf][4 + e] = (__bf16)u1[e]; }
    }
  } else {
#pragma unroll
    for (int i = 0; i < 8; ++i)
#pragma unroll
      for (int e = 0; e < 8; ++e) alow[i][e] = (__bf16)0.f;
#pragma unroll
    for (int j = 0; j < 4; ++j)
#pragma unroll
      for (int e = 0; e < 8; ++e) blow[j][e] = (__bf16)0.f;
  }
#pragma unroll
  for (int mf = 0; mf < 8; ++mf)
#pragma unroll
    for (int nf = 0; nf < 4; ++nf)
      acc[mf][nf] = __builtin_amdgcn_mfma_f32_16x16x32_bf16(alow[mf], blow[nf], acc[mf][nf], 0, 0, 0);

  // ---- bias + store (C/D layout: col = lane&15, row = quad*4 + reg) ------
#pragma unroll
  for (int nf = 0; nf < 4; ++nf) {
    const int c = n0 + wn * 64 + nf * 16 + l16;
    const float bc = bias[c];
#pragma unroll
    for (int mf = 0; mf < 8; ++mf) {
      const int r0 = m0 + wm * 128 + mf * 16 + quad * 4;
#pragma unroll
      for (int e = 0; e < 4; ++e)
        out[(size_t)(r0 + e) * DOUT + c] = acc[mf][nf][e] + bc;
    }
  }
}

extern "C" void kernel_launch(void* const* d_in, const int* in_sizes, int n_in,
                              void* d_out, int out_size, void* d_ws, size_t ws_size,
                              hipStream_t stream) {
  const float* x       = (const float*)d_in[0];
  const float* weight  = (const float*)d_in[1];
  const float* bias    = (const float*)d_in[2];
  const float* lora_a  = (const float*)d_in[3];
  const float* lora_b  = (const float*)d_in[4];
  const float* scaling = (const float*)d_in[5];
  const int*   adapter = (const int*)d_in[6];
  float* out = (float*)d_out;

  // workspace layout: x_bf16 (64 MiB) | W_bf16 (32 MiB) | lowS (512 KiB)
  __bf16* xb   = (__bf16*)d_ws;
  __bf16* wb   = xb + (size_t)MTOT * DIN;
  float*  lowS = (float*)(wb + (size_t)DOUT * DIN);

  hipMemsetAsync(lowS, 0, (size_t)MTOT * RANK * sizeof(float), stream);
  conv_kernel<<<(size_t)DOUT * DIN / 8 / 256, 256, 0, stream>>>(weight, wb);
  conv_kernel<<<(size_t)MTOT * DIN / 8 / 256, 256, 0, stream>>>(x, xb);
  dim3 lgrid(MTOT / 64, 8);
  lora_low_kernel<<<lgrid, 256, 0, stream>>>(xb, lora_a, scaling, adapter, lowS);
  dim3 grid(DOUT / BN, MTOT / BM);
  lora_gemm_kernel<<<grid, 512, 0, stream>>>(xb, wb, bias, lora_b, adapter, lowS, out);
}

// Round 2
// 504.031 us; speedup vs baseline: 1.3253x; 1.1059x over previous
//
#include <hip/hip_runtime.h>
#include <hip/hip_bf16.h>

// ---- problem constants ----
#define BATCH 4
#define SEQ   2048
#define DIN   4096
#define DOUT  4096
#define MTOT  (BATCH * SEQ)     // 8192
#define RANK  16

typedef __bf16 bf8_t  __attribute__((ext_vector_type(8)));
typedef float  f4_t   __attribute__((ext_vector_type(4)));

#define GLD_LDS(g, l) \
  __builtin_amdgcn_global_load_lds((const __attribute__((address_space(1))) void*)(g), \
                                   (__attribute__((address_space(3))) void*)(l), 16, 0, 0)

// ---------------------------------------------------------------------------
// Kernel A: convert weight f32 -> bf16 (coalesced, 8/thread)
// ---------------------------------------------------------------------------
__global__ __launch_bounds__(256) void conv_w_kernel(
    const float* __restrict__ w, __bf16* __restrict__ wb) {
  const size_t i = ((size_t)blockIdx.x * 256 + threadIdx.x) * 8;
  f4_t a = *(const f4_t*)(w + i);
  f4_t b = *(const f4_t*)(w + i + 4);
  bf8_t o;
#pragma unroll
  for (int e = 0; e < 4; ++e) { o[e] = (__bf16)a[e]; o[4 + e] = (__bf16)b[e]; }
  *(bf8_t*)(wb + i) = o;
}

// ---------------------------------------------------------------------------
// Kernel B (round-0 fused, verified): lowS[m][r] += scale * x[m][:]·A[b][r][:]
// Reads x f32 once, emits xb bf16 in-flight (fused conversion). k-split=8.
// lowS must be zeroed before launch.
// ---------------------------------------------------------------------------
__global__ __launch_bounds__(256) void lora_low_kernel(
    const float* __restrict__ x, const float* __restrict__ Aw,
    const float* __restrict__ scales, const int* __restrict__ adapter_id,
    __bf16* __restrict__ xb, float* __restrict__ lowS) {
  const int t    = threadIdx.x;
  const int w    = t >> 6;
  const int lane = t & 63;
  const int quad = lane >> 4;
  const int l16  = lane & 15;
  const int m0   = blockIdx.x * 64;
  const int kb   = blockIdx.y * 512;
  const int b    = adapter_id[m0 >> 11];
  const float scale = scales[b];

  const int row = m0 + w * 16 + l16;
  const float*  xp  = x  + (size_t)row * DIN + kb + quad * 8;
  __bf16*       xbp = xb + (size_t)row * DIN + kb + quad * 8;
  const float*  ap  = Aw + ((size_t)b * RANK + l16) * DIN + kb + quad * 8;

  f4_t acc = (f4_t)0.f;
#pragma unroll 4
  for (int it = 0; it < 16; ++it) {
    const int off = it * 32;
    f4_t u0 = *(const f4_t*)(xp + off);
    f4_t u1 = *(const f4_t*)(xp + off + 4);
    f4_t v0 = *(const f4_t*)(ap + off);
    f4_t v1 = *(const f4_t*)(ap + off + 4);
    bf8_t af, bfr;
#pragma unroll
    for (int e = 0; e < 4; ++e) {
      af[e] = (__bf16)u0[e]; af[4 + e] = (__bf16)u1[e];
      bfr[e] = (__bf16)v0[e]; bfr[4 + e] = (__bf16)v1[e];
    }
    *(bf8_t*)(xbp + off) = af;   // fused x f32->bf16 emission
    acc = __builtin_amdgcn_mfma_f32_16x16x32_bf16(af, bfr, acc, 0, 0, 0);
  }
#pragma unroll
  for (int e = 0; e < 4; ++e)
    atomicAdd(&lowS[(size_t)(m0 + w * 16 + quad * 4 + e) * RANK + l16], acc[e] * scale);
}

// ---------------------------------------------------------------------------
// Kernel C: out = x @ W^T + bias + lowS @ loraB[b]^T   (bf16 GEMM, f32 out)
// 256x256 tile, BK=64, 8 waves (2M x 4N), 8-phase schedule (m201 template):
// per phase {ds-read quadrant subtile || stage 1 half-tile -> barrier ->
// setprio(1) 16xMFMA setprio(0) -> barrier}, counted vmcnt(4) at phases 4/8
// only. 2 buffers x {A,B} x {half0,half1} of 128x64 bf16 = 128 KiB LDS.
// Read swizzle: stored_chunk = logical ^ ((row>>1)&7), inverse-applied on the
// global source so global_load_lds stays linear. 2-way LDS reads (free).
// ---------------------------------------------------------------------------
#define BM 256
#define BN 256
#define BKT 64
#define NT (DIN / BKT)   // 64 K-tiles
#define NIT (NT / 2)     // 32 iterations x 2 tiles

#define BAR() __builtin_amdgcn_s_barrier()
#define VMW(n) asm volatile("s_waitcnt vmcnt(" #n ")" ::: "memory")

__global__ __launch_bounds__(512, 2) void lora_gemm_kernel(
    const __bf16* __restrict__ x, const __bf16* __restrict__ wgt,
    const float* __restrict__ bias, const float* __restrict__ loraB,
    const int* __restrict__ adapter_id, const float* __restrict__ lowS,
    float* __restrict__ out) {
  __shared__ __bf16 lds[2][2][2][128 * 64];  // [buf][A/B][half][128 rows x 64 k]

  const int t    = threadIdx.x;
  const int w    = t >> 6;
  const int lane = t & 63;
  const int quad = lane >> 4;
  const int l16  = lane & 15;
  const int wm   = w >> 2;        // 0..1 : 128-row band (== A half)
  const int wn   = w & 3;         // 0..3 : 64-col band  (B half = wn>>1)

  // XCD-aware bijective swizzle: 512 blocks, 8 XCDs, 64 blocks/XCD contiguous.
  const int linear = blockIdx.y * 16 + blockIdx.x;      // gridDim.x == 16
  const int swz = (linear & 7) * 64 + (linear >> 3);
  const int m0 = (swz >> 4) * BM;
  const int n0 = (swz & 15) * BN;

  // ---- staging addresses (per 64-row issue) -----------------------------
  // thread t covers row srow = t>>3 (0..63), LDS chunk (t&7); source chunk is
  // inverse-swizzled: sc = (t&7) ^ ((row>>1)&7), (row>>1)&7 == (t>>4)&7.
  const int srow = t >> 3;
  const int sc   = (t & 7) ^ ((t >> 4) & 7);
  const __bf16* gA = x   + (size_t)(m0 + srow) * DIN + sc * 8;
  const __bf16* gB = wgt + (size_t)(n0 + srow) * DIN + sc * 8;
  const int ldsw = w * 512;       // wave-uniform elem offset; HW adds lane*16B

#define STG(buf, mat, half, kel, gp) do {                                        \
    GLD_LDS((gp) + (size_t)((half) * 128) * DIN + (kel),                         \
            &lds[buf][mat][half][ldsw]);                                         \
    GLD_LDS((gp) + (size_t)((half) * 128 + 64) * DIN + (kel),                    \
            &lds[buf][mat][half][4096 + ldsw]);                                  \
  } while (0)

  // ---- fragment-read offsets: stored chunk = (ks*4+quad) ^ ((l16>>1)&7) --
  const int st0 = (quad ^ ((l16 >> 1) & 7)) * 8;
  const int st1 = ((4 + quad) ^ ((l16 >> 1) & 7)) * 8;

  bf8_t a[4][2], b[2][2];
  f4_t acc[8][4];
#pragma unroll
  for (int i = 0; i < 8; ++i)
#pragma unroll
    for (int j = 0; j < 4; ++j) acc[i][j] = (f4_t)0.f;

#define LDA(buf, mh) do {                                                        \
    const __bf16* base_ = &lds[buf][0][wm][0];                                   \
    _Pragma("unroll")                                                            \
    for (int mq = 0; mq < 4; ++mq) {                                             \
      const int r_ = ((mh) * 4 + mq) * 16 + l16;                                 \
      a[mq][0] = *(const bf8_t*)(base_ + r_ * 64 + st0);                         \
      a[mq][1] = *(const bf8_t*)(base_ + r_ * 64 + st1);                         \
    }                                                                            \
  } while (0)

#define LDB(buf, nh) do {                                                        \
    const __bf16* base_ = &lds[buf][1][wn >> 1][(wn & 1) * 4096];                \
    _Pragma("unroll")                                                            \
    for (int nq = 0; nq < 2; ++nq) {                                             \
      const int r_ = ((nh) * 2 + nq) * 16 + l16;                                 \
      b[nq][0] = *(const bf8_t*)(base_ + r_ * 64 + st0);                         \
      b[nq][1] = *(const bf8_t*)(base_ + r_ * 64 + st1);                         \
    }                                                                            \
  } while (0)

#define MM(mh, nh) do {                                                          \
    __builtin_amdgcn_s_setprio(1);                                               \
    _Pragma("unroll")                                                            \
    for (int ks = 0; ks < 2; ++ks)                                               \
      _Pragma("unroll")                                                          \
      for (int mq = 0; mq < 4; ++mq)                                             \
        _Pragma("unroll")                                                        \
        for (int nq = 0; nq < 2; ++nq)                                           \
          acc[(mh) * 4 + mq][(nh) * 2 + nq] = __builtin_amdgcn_mfma_f32_16x16x32_bf16( \
              a[mq][ks], b[nq][ks], acc[(mh) * 4 + mq][(nh) * 2 + nq], 0, 0, 0); \
    __builtin_amdgcn_s_setprio(0);                                               \
  } while (0)

  // ---- prologue: tile0 all 4 halves + tile1 {Ah0, Bh1}; confirm tile0 ----
  STG(0, 0, 0, 0, gA); STG(0, 0, 1, 0, gA);
  STG(0, 1, 0, 0, gB); STG(0, 1, 1, 0, gB);
  STG(1, 0, 0, BKT, gA); STG(1, 1, 1, BKT, gB);
  VMW(4);
  BAR();

  // ---- 8-phase main loop (2 K-tiles / iter) ------------------------------
  for (int it = 0; it < NIT; ++it) {
    const int k1 = (2 * it + 1) * BKT;
    const int k2 = ((2 * it + 2) & (NT - 1)) * BKT;   // wrap: last-iter stages
    const int k3 = ((2 * it + 3) & (NT - 1)) * BKT;   // are garbage, never read
    // P1: quadrant (0,0) of tile t (buf0); stage Bh0(t+1)
    LDA(0, 0); LDB(0, 0); STG(1, 1, 0, k1, gB);
    BAR(); MM(0, 0); BAR();
    // P2: (0,1); stage Ah1(t+1)
    LDB(0, 1); STG(1, 0, 1, k1, gA);
    BAR(); MM(0, 1); BAR();
    // P3: (1,1); stage Ah0(t+2)
    LDA(0, 1); STG(0, 0, 0, k2, gA);
    BAR(); MM(1, 1); BAR();
    // P4: (1,0); stage Bh1(t+2); confirm tile t+1 resident
    LDB(0, 0); STG(0, 1, 1, k2, gB);
    VMW(4);
    BAR(); MM(1, 0); BAR();
    // P5: quadrant (0,0) of tile t+1 (buf1); stage Bh0(t+2)
    LDA(1, 0); LDB(1, 0); STG(0, 1, 0, k2, gB);
    BAR(); MM(0, 0); BAR();
    // P6: (0,1); stage Ah1(t+2)
    LDB(1, 1); STG(0, 0, 1, k2, gA);
    BAR(); MM(0, 1); BAR();
    // P7: (1,1); stage Ah0(t+3)
    LDA(1, 1); STG(1, 0, 0, k3, gA);
    BAR(); MM(1, 1); BAR();
    // P8: (1,0); stage Bh1(t+3); confirm tile t+2 resident
    LDB(1, 0); STG(1, 1, 1, k3, gB);
    VMW(4);
    BAR(); MM(1, 0); BAR();
  }
#undef STG
#undef LDA
#undef LDB
#undef MM

  // ---- LoRA epilogue: one zero-padded MFMA k-step (k=0..15 valid) --------
  const int b_id = adapter_id[m0 >> 11];
  bf8_t alow[8], blow[4];
  if (quad < 2) {
#pragma unroll
    for (int mf = 0; mf < 8; ++mf) {
      const float* p = &lowS[(size_t)(m0 + wm * 128 + mf * 16 + l16) * RANK + quad * 8];
      f4_t u0 = *(const f4_t*)p;
      f4_t u1 = *(const f4_t*)(p + 4);
#pragma unroll
      for (int e = 0; e < 4; ++e) { alow[mf][e] = (__bf16)u0[e]; alow[mf][4 + e] = (__bf16)u1[e]; }
    }
#pragma unroll
    for (int nf = 0; nf < 4; ++nf) {
      const float* p = &loraB[((size_t)b_id * DOUT + n0 + wn * 64 + nf * 16 + l16) * RANK + quad * 8];
      f4_t u0 = *(const f4_t*)p;
      f4_t u1 = *(const f4_t*)(p + 4);
#pragma unroll
      for (int e = 0; e < 4; ++e) { blow[nf][e] = (__bf16)u0[e]; blow[nf][4 + e] = (__bf16)u1[e]; }
    }
  } else {
#pragma unroll
    for (int i = 0; i < 8; ++i)
#pragma unroll
      for (int e = 0; e < 8; ++e) alow[i][e] = (__bf16)0.f;
#pragma unroll
    for (int j = 0; j < 4; ++j)
#pragma unroll
      for (int e = 0; e < 8; ++e) blow[j][e] = (__bf16)0.f;
  }
#pragma unroll
  for (int mf = 0; mf < 8; ++mf)
#pragma unroll
    for (int nf = 0; nf < 4; ++nf)
      acc[mf][nf] = __builtin_amdgcn_mfma_f32_16x16x32_bf16(alow[mf], blow[nf], acc[mf][nf], 0, 0, 0);

  // ---- bias + store (C/D layout: col = lane&15, row = quad*4 + reg) ------
#pragma unroll
  for (int nf = 0; nf < 4; ++nf) {
    const int c = n0 + wn * 64 + nf * 16 + l16;
    const float bc = bias[c];
#pragma unroll
    for (int mf = 0; mf < 8; ++mf) {
      const int r0 = m0 + wm * 128 + mf * 16 + quad * 4;
#pragma unroll
      for (int e = 0; e < 4; ++e)
        out[(size_t)(r0 + e) * DOUT + c] = acc[mf][nf][e] + bc;
    }
  }
}

extern "C" void kernel_launch(void* const* d_in, const int* in_sizes, int n_in,
                              void* d_out, int out_size, void* d_ws, size_t ws_size,
                              hipStream_t stream) {
  const float* x       = (const float*)d_in[0];
  const float* weight  = (const float*)d_in[1];
  const float* bias    = (const float*)d_in[2];
  const float* lora_a  = (const float*)d_in[3];
  const float* lora_b  = (const float*)d_in[4];
  const float* scaling = (const float*)d_in[5];
  const int*   adapter = (const int*)d_in[6];
  float* out = (float*)d_out;

  // workspace layout: x_bf16 (64 MiB) | W_bf16 (32 MiB) | lowS (512 KiB)
  __bf16* xb   = (__bf16*)d_ws;
  __bf16* wb   = xb + (size_t)MTOT * DIN;
  float*  lowS = (float*)(wb + (size_t)DOUT * DIN);

  hipMemsetAsync(lowS, 0, (size_t)MTOT * RANK * sizeof(float), stream);
  conv_w_kernel<<<(size_t)DOUT * DIN / 8 / 256, 256, 0, stream>>>(weight, wb);
  dim3 lgrid(MTOT / 64, 8);
  lora_low_kernel<<<lgrid, 256, 0, stream>>>(x, lora_a, scaling, adapter, xb, lowS);
  dim3 grid(DOUT / BN, MTOT / BM);
  lora_gemm_kernel<<<grid, 512, 0, stream>>>(xb, wb, bias, lora_b, adapter, lowS, out);
}